// Round 4
// baseline (194.341 us; speedup 1.0000x reference)
//
#include <hip/hip_runtime.h>
#include <math.h>

// Problem constants
#define NB 8
#define NN 225
#define NT 1800          // NB*NN
#define NE 14400
#define NP 50625         // NN*NN
#define HA 32
#define HC 32
#define BN_EPS 1e-5f

#define RPB 9            // rows per block (200*9 = 1800)
#define NBLK 200
#define NTHR 256
#define LCAP 384         // edge-hit list capacity (mean 72)

// -------- workspace layout (float offsets); nothing needs pre-zeroing --------
#define WS_TPRE1 0        // 1800*64 = 115200
#define WS_P1    115200   // 1800*32
#define WS_P2    172800   // 1800*32
#define WS_P1S   230400   // 200*64 BN1 sum partials
#define WS_P1Q   243200   // 200*64 BN1 sq partials
#define WS_PEMB  256000   // 200*64 pooling partials
#define WS_SACC  268800   // 8 floats: per-batch softmax denom (zeroed by K2)
#define WS_CNT   268808   // 8 ints: per-batch arrival counters (zeroed by K2)

// ==== K1: GIN0 (full local agg + analytic BN0 stats) + GIN1-gather + lin1 + BN1 partials ====
// Key algebra: tpre0 = u@w1+b1 with u 2-dim => BN0 stats from 5 scalar moments of u
// (block-local). z = y0[own] + sum_e y0[src_e]; layer-1 input row = z@g0_w2 + (1+deg)*g0_b2.
// tpre0/h1 never hit global memory.
__global__ void __launch_bounds__(NTHR) k_gin01(const float* __restrict__ x,
                                                const int* __restrict__ ei,
                                                const float* __restrict__ g0_w1,
                                                const float* __restrict__ g0_b1,
                                                const float* __restrict__ g0_gamma,
                                                const float* __restrict__ g0_beta,
                                                const float* __restrict__ g0_w2,
                                                const float* __restrict__ g0_b2,
                                                const float* __restrict__ g1_w1,
                                                const float* __restrict__ g1_b1,
                                                float* __restrict__ tpre1,
                                                float* __restrict__ p1s,
                                                float* __restrict__ p1q) {
    __shared__ float xs[NT * 2];      // 14.4 KB
    __shared__ float us[NT * 2];      // 14.4 KB (agg, then u = x+agg)
    __shared__ float w2s[4096];       // g0_w2
    __shared__ float w1s[4096];       // g1_w1
    __shared__ float z[RPB * 64];
    __shared__ float t1[RPB * 64];
    __shared__ int   list[LCAP];
    __shared__ int   degs[RPB];
    __shared__ int   cnt;
    __shared__ float mom[20];         // 4 waves x 5 moments
    __shared__ float bn0[128];        // m_c, inv_c
    __shared__ float red[512];

    const int t = threadIdx.x, base = blockIdx.x * RPB;
    const int c = t & 63, rg = t >> 6;

    if (t == 0) cnt = 0;
    if (t < RPB) degs[t] = 0;
    for (int i = t; i < NT * 2; i += NTHR) { xs[i] = x[i]; us[i] = 0.f; }
    for (int i = t; i < 4096; i += NTHR) { w2s[i] = g0_w2[i]; w1s[i] = g1_w1[i]; }
    __syncthreads();

    // full scatter into LDS + own-row hit list
    for (int e = t; e < NE; e += NTHR) {
        int src = ei[e], dst = ei[NE + e];
        float2 xv = ((const float2*)xs)[src];
        atomicAdd(&us[dst * 2],     xv.x);
        atomicAdd(&us[dst * 2 + 1], xv.y);
        unsigned d = (unsigned)(dst - base);
        if (d < RPB) {
            int idx = atomicAdd(&cnt, 1);
            list[idx] = (int)((d << 16) | (unsigned)src);
            atomicAdd(&degs[d], 1);
        }
    }
    __syncthreads();
    for (int i = t; i < NT * 2; i += NTHR) us[i] += xs[i];
    __syncthreads();

    // 5 global moments of u (local reduce)
    float s0 = 0, s1 = 0, q00 = 0, q11 = 0, q01 = 0;
    for (int r = t; r < NT; r += NTHR) {
        float u0 = us[r * 2], u1 = us[r * 2 + 1];
        s0 += u0; s1 += u1; q00 += u0 * u0; q11 += u1 * u1; q01 += u0 * u1;
    }
    for (int off = 32; off > 0; off >>= 1) {
        s0 += __shfl_down(s0, off);   s1 += __shfl_down(s1, off);
        q00 += __shfl_down(q00, off); q11 += __shfl_down(q11, off);
        q01 += __shfl_down(q01, off);
    }
    if (c == 0) {
        mom[rg * 5] = s0; mom[rg * 5 + 1] = s1; mom[rg * 5 + 2] = q00;
        mom[rg * 5 + 3] = q11; mom[rg * 5 + 4] = q01;
    }
    __syncthreads();
    if (t < 64) {
        float S0 = mom[0] + mom[5] + mom[10] + mom[15];
        float S1 = mom[1] + mom[6] + mom[11] + mom[16];
        float Q00 = mom[2] + mom[7] + mom[12] + mom[17];
        float Q11 = mom[3] + mom[8] + mom[13] + mom[18];
        float Q01 = mom[4] + mom[9] + mom[14] + mom[19];
        const float inN = 1.f / NT;
        float mu0 = S0 * inN, mu1 = S1 * inN;
        float c00 = Q00 * inN - mu0 * mu0;
        float c11 = Q11 * inN - mu1 * mu1;
        float c01 = Q01 * inN - mu0 * mu1;
        float w0 = g0_w1[t], w1c = g0_w1[64 + t];
        bn0[t] = g0_b1[t] + mu0 * w0 + mu1 * w1c;                       // channel mean
        float var = w0 * w0 * c00 + 2.f * w0 * w1c * c01 + w1c * w1c * c11;
        bn0[64 + t] = rsqrtf(var + BN_EPS);
    }
    __syncthreads();

    const float w0 = g0_w1[c], w1c = g0_w1[64 + c], b1c = g0_b1[c];
    const float m0 = bn0[c], iv0 = bn0[64 + c];
    const float ga = g0_gamma[c], be = g0_beta[c];
    // z init: own rows' y0
    for (int rr = rg; rr < RPB; rr += 4) {
        int r = base + rr;
        float pre = b1c + us[r * 2] * w0 + us[r * 2 + 1] * w1c;
        z[rr * 64 + c] = fmaxf((pre - m0) * iv0 * ga + be, 0.f);
    }
    __syncthreads();
    // neighbor y0 contributions (y0 is elementwise from 2-dim u — cheap)
    for (int h = rg; h < cnt; h += 4) {
        int pk = list[h];
        int rr = pk >> 16, src = pk & 0xFFFF;
        float pre = b1c + us[src * 2] * w0 + us[src * 2 + 1] * w1c;
        float y = fmaxf((pre - m0) * iv0 * ga + be, 0.f);
        atomicAdd(&z[rr * 64 + c], y);
    }
    __syncthreads();
    // layer-1 input = z@g0_w2 + (1+deg)*g0_b2
    const float b2c = g0_b2[c];
    for (int rr = rg; rr < RPB; rr += 4) {
        float acc = (1.f + (float)degs[rr]) * b2c;
#pragma unroll
        for (int k = 0; k < 64; ++k) acc += z[rr * 64 + k] * w2s[k * 64 + c];
        t1[rr * 64 + c] = acc;
    }
    __syncthreads();
    // tpre1 = t1@g1_w1 + b1 ; BN1 stat partials
    const float b1g = g1_b1[c];
    float ls = 0.f, lq = 0.f;
    for (int rr = rg; rr < RPB; rr += 4) {
        float acc = b1g;
#pragma unroll
        for (int k = 0; k < 64; ++k) acc += t1[rr * 64 + k] * w1s[k * 64 + c];
        tpre1[(base + rr) * 64 + c] = acc;
        ls += acc; lq += acc * acc;
    }
    red[t] = ls; red[256 + t] = lq;
    __syncthreads();
    if (t < 64) {
        p1s[blockIdx.x * 64 + t] = red[t] + red[64 + t] + red[128 + t] + red[192 + t];
        p1q[blockIdx.x * 64 + t] = red[256 + t] + red[320 + t] + red[384 + t] + red[448 + t];
    }
}

// ==== K2: BN1 finalize + ReLU + linear 64->64 -> feats + P1/P2 projections + emb partials ====
__global__ void __launch_bounds__(NTHR) k_bnlin1proj(const float* __restrict__ tpre,
                                                     const float* __restrict__ p1s,
                                                     const float* __restrict__ p1q,
                                                     const float* __restrict__ gamma,
                                                     const float* __restrict__ beta,
                                                     const float* __restrict__ w2,
                                                     const float* __restrict__ b2,
                                                     const float* __restrict__ a_w1,
                                                     float* __restrict__ P1,
                                                     float* __restrict__ P2,
                                                     float* __restrict__ pemb,
                                                     float* __restrict__ Sacc,
                                                     int* __restrict__ cntb) {
    __shared__ float y[RPB * 64];
    __shared__ float f[RPB * 64];
    __shared__ float w2s[4096];
    __shared__ float aw1s[4096];
    __shared__ float red[512];
    __shared__ float mi[128];
    const int t = threadIdx.x, base = blockIdx.x * RPB;
    const int c = t & 63, rg = t >> 6;
    // zero the K3 barrier state (visible to K3 via kernel-boundary flush)
    if (blockIdx.x < NB && t == 0) { Sacc[blockIdx.x] = 0.f; cntb[blockIdx.x] = 0; }
    for (int i = t; i < 4096; i += NTHR) { w2s[i] = w2[i]; aw1s[i] = a_w1[64 * HA + i]; }
    float ls = 0.f, lq = 0.f;
    for (int p = rg; p < NBLK; p += 4) { ls += p1s[p * 64 + c]; lq += p1q[p * 64 + c]; }
    red[t] = ls; red[256 + t] = lq;
    __syncthreads();
    if (t < 64) {
        float S = red[t] + red[64 + t] + red[128 + t] + red[192 + t];
        float Q = red[256 + t] + red[320 + t] + red[384 + t] + red[448 + t];
        float m = S * (1.f / NT);
        mi[t] = m;
        mi[64 + t] = rsqrtf(Q * (1.f / NT) - m * m + BN_EPS);
    }
    __syncthreads();
    float m = mi[c], inv = mi[64 + c], ga = gamma[c], be = beta[c];
    for (int rr = rg; rr < RPB; rr += 4) {
        float yv = (tpre[(base + rr) * 64 + c] - m) * inv * ga + be;
        y[rr * 64 + c] = fmaxf(yv, 0.f);
    }
    __syncthreads();
    float bc = b2[c];
    for (int rr = rg; rr < RPB; rr += 4) {
        float acc = bc;
#pragma unroll
        for (int k = 0; k < 64; ++k) acc += y[rr * 64 + k] * w2s[k * 64 + c];
        f[rr * 64 + c] = acc;
    }
    __syncthreads();
    if (t < 64) {    // pooling partial (block's 9 rows are same batch: 225 = 25*9)
        float pe = 0.f;
#pragma unroll
        for (int rr = 0; rr < RPB; ++rr) pe += f[rr * 64 + t];
        pemb[blockIdx.x * 64 + t] = pe;
    }
    int j = c & 31;
    const float* wb = (c < 32) ? aw1s : (aw1s + 64 * HA);
    for (int rr = rg; rr < RPB; rr += 4) {
        float p = 0.f;
#pragma unroll
        for (int k = 0; k < 64; ++k) p += f[rr * 64 + k] * wb[k * HA + j];
        if (c < 32) P1[(base + rr) * HA + j] = p;
        else        P2[(base + rr) * HA + j] = p;
    }
}

// ==== K3: pooled emb + Ps + critic + pairwise exp(logits) + per-batch device barrier + pi ====
__global__ void __launch_bounds__(NTHR) k_pairs(const float* __restrict__ P1,
                                                const float* __restrict__ P2,
                                                const float* __restrict__ pemb,
                                                const float* __restrict__ a_w1,
                                                const float* __restrict__ a_b1,
                                                const float* __restrict__ a_w2,
                                                const float* __restrict__ a_b2,
                                                const float* __restrict__ c_w1,
                                                const float* __restrict__ c_b1,
                                                const float* __restrict__ c_w2,
                                                const float* __restrict__ c_b2,
                                                float* __restrict__ Sacc,
                                                int* __restrict__ cntb,
                                                float* __restrict__ pi,
                                                float* __restrict__ value_out) {
    __shared__ float Q1[NN * 36];    // Ps+P1, stride 36 (16B-aligned)
    __shared__ float P2s[RPB * HA];
    __shared__ float emb[64];
    __shared__ float Psl[32];
    __shared__ float w2l[32];
    __shared__ float hv[32];
    __shared__ float red[256];
    __shared__ float invS;
    const int t = threadIdx.x;
    const int b = blockIdx.x / 25, chunk = blockIdx.x % 25;
    if (t < 64) {
        float s = 0.f;
#pragma unroll
        for (int q = 0; q < 25; ++q) s += pemb[(b * 25 + q) * 64 + t];
        emb[t] = s * (1.f / NN);
    }
    __syncthreads();
    if (t < 32) {
        float a = a_b1[t];
#pragma unroll
        for (int m = 0; m < 64; ++m) a += emb[m] * a_w1[m * HA + t];
        Psl[t] = a;
        w2l[t] = a_w2[t];
    } else if (t < 64 && chunk == 0) {
        int j = t - 32;
        float a = c_b1[j];
#pragma unroll
        for (int m = 0; m < 64; ++m) a += emb[m] * c_w1[m * HC + j];
        hv[j] = fmaxf(a, 0.f);
    }
    __syncthreads();
    if (chunk == 0 && t == 0) {
        float a = c_b2[0];
#pragma unroll
        for (int j = 0; j < HC; ++j) a += hv[j] * c_w2[j];
        value_out[b] = a;
    }
    for (int idx = t; idx < NN * HA; idx += NTHR) {
        int j = idx >> 5, k = idx & 31;
        Q1[j * 36 + k] = Psl[k] + P1[(b * NN + j) * HA + k];
    }
    for (int idx = t; idx < RPB * HA; idx += NTHR)
        P2s[idx] = P2[(b * NN + chunk * RPB) * HA + idx];
    __syncthreads();
    const float bias2 = a_b2[0];
    float ev[8];
    float ls = 0.f;
    for (int p = t, it = 0; p < 2025; p += NTHR, ++it) {
        int i = p / 225, j = p - i * 225;
        const float4* q4 = (const float4*)&Q1[j * 36];
        const float4* p4 = (const float4*)&P2s[i * HA];
        const float4* w4 = (const float4*)w2l;
        float acc = bias2;
#pragma unroll
        for (int k4 = 0; k4 < 8; ++k4) {
            float4 q = q4[k4], pp = p4[k4], w = w4[k4];
            acc += fmaxf(q.x + pp.x, 0.f) * w.x;
            acc += fmaxf(q.y + pp.y, 0.f) * w.y;
            acc += fmaxf(q.z + pp.z, 0.f) * w.z;
            acc += fmaxf(q.w + pp.w, 0.f) * w.w;
        }
        float e = expf(acc);    // logits O(1): no max-subtraction needed in fp32
        ev[it] = e;
        ls += e;
    }
    red[t] = ls;
    __syncthreads();
    for (int s = 128; s > 0; s >>= 1) {
        if (t < s) red[t] += red[t + s];
        __syncthreads();
    }
    // per-batch lightweight device barrier: ev stays in registers across it
    if (t == 0) {
        atomicAdd(&Sacc[b], red[0]);          // device-scope by default
        __threadfence();                       // release partial before arrive
        atomicAdd(&cntb[b], 1);
        int spins = 0;
        while (__hip_atomic_load(&cntb[b], __ATOMIC_RELAXED, __HIP_MEMORY_SCOPE_AGENT) < 25
               && spins < (1 << 18)) ++spins;  // bounded: safety valve for profiler replay
        __threadfence();                       // acquire
        invS = 1.f / __hip_atomic_load(&Sacc[b], __ATOMIC_RELAXED, __HIP_MEMORY_SCOPE_AGENT);
    }
    __syncthreads();
    const float inv = invS;
    float* outp = pi + b * NP + chunk * 2025;
    for (int p = t, it = 0; p < 2025; p += NTHR, ++it)
        outp[p] = ev[it] * inv;
}

extern "C" void kernel_launch(void* const* d_in, const int* in_sizes, int n_in,
                              void* d_out, int out_size, void* d_ws, size_t ws_size,
                              hipStream_t stream) {
    const float* x        = (const float*)d_in[0];
    const int*   ei       = (const int*)d_in[1];
    // d_in[2] = batch_ids (unused: graphs are contiguous 225-node blocks)
    const float* g0_w1    = (const float*)d_in[3];
    const float* g0_b1    = (const float*)d_in[4];
    const float* g0_gamma = (const float*)d_in[5];
    const float* g0_beta  = (const float*)d_in[6];
    const float* g0_w2    = (const float*)d_in[7];
    const float* g0_b2    = (const float*)d_in[8];
    const float* g1_w1    = (const float*)d_in[9];
    const float* g1_b1    = (const float*)d_in[10];
    const float* g1_gamma = (const float*)d_in[11];
    const float* g1_beta  = (const float*)d_in[12];
    const float* g1_w2    = (const float*)d_in[13];
    const float* g1_b2    = (const float*)d_in[14];
    const float* a_w1     = (const float*)d_in[15];
    const float* a_b1     = (const float*)d_in[16];
    const float* a_w2     = (const float*)d_in[17];
    const float* a_b2     = (const float*)d_in[18];
    const float* c_w1     = (const float*)d_in[19];
    const float* c_b1     = (const float*)d_in[20];
    const float* c_w2     = (const float*)d_in[21];
    const float* c_b2     = (const float*)d_in[22];

    float* ws    = (float*)d_ws;
    float* tpre1 = ws + WS_TPRE1;
    float* P1    = ws + WS_P1;
    float* P2    = ws + WS_P2;
    float* p1s   = ws + WS_P1S;
    float* p1q   = ws + WS_P1Q;
    float* pemb  = ws + WS_PEMB;
    float* Sacc  = ws + WS_SACC;
    int*   cntb  = (int*)(ws + WS_CNT);

    float* pi        = (float*)d_out;            // [8, 50625]
    float* value_out = (float*)d_out + NB * NP;  // [8]

    k_gin01<<<NBLK, NTHR, 0, stream>>>(x, ei, g0_w1, g0_b1, g0_gamma, g0_beta,
                                       g0_w2, g0_b2, g1_w1, g1_b1, tpre1, p1s, p1q);
    k_bnlin1proj<<<NBLK, NTHR, 0, stream>>>(tpre1, p1s, p1q, g1_gamma, g1_beta,
                                            g1_w2, g1_b2, a_w1, P1, P2, pemb, Sacc, cntb);
    k_pairs<<<NBLK, NTHR, 0, stream>>>(P1, P2, pemb, a_w1, a_b1, a_w2, a_b2,
                                       c_w1, c_b1, c_w2, c_b2, Sacc, cntb, pi, value_out);
}

// Round 5
// 179.045 us; speedup vs baseline: 1.0854x; 1.0854x over previous
//
#include <hip/hip_runtime.h>
#include <math.h>

// Problem constants
#define NB 8
#define NN 225
#define NT 1800          // NB*NN
#define NE 14400
#define NP 50625         // NN*NN
#define HA 32
#define HC 32
#define BN_EPS 1e-5f

#define RPB 9            // rows per block (200*9 = 1800)
#define NBLK 200
#define NTHR 256
#define LCAP 384         // edge-hit list capacity (mean 72, ~36 sigma headroom)

// -------- workspace layout (float offsets); nothing needs pre-zeroing --------
#define WS_U     0        // 1800*2 = 3600 (u = x + agg0)
#define WS_PMOM  3600     // 200*5 moment partials
#define WS_DEG   4600     // 1800 (degree, stored as float)
#define WS_GL    6400     // 200*LCAP ints (per-block edge-hit lists)
#define WS_GCNT  83200    // 200 ints
#define WS_TPRE1 83400    // 1800*64 = 115200
#define WS_P1    198600   // 1800*32
#define WS_P2    256200   // 1800*32
#define WS_P1S   313800   // 200*64 BN1 sum partials
#define WS_P1Q   326600   // 200*64 BN1 sq partials
#define WS_PEMB  339400   // 200*64 pooling partials
#define WS_SACC  352200   // 8 floats: per-batch softmax denom (zeroed by K2)
#define WS_CNT   352208   // 8 ints: per-batch arrival counters (zeroed by K2)

// ==== K0: layer-0 aggregation (gather) + u + 5-moment partials + edge-hit list to global ====
__global__ void __launch_bounds__(NTHR) k_agg0(const float* __restrict__ x,
                                               const int* __restrict__ ei,
                                               float* __restrict__ u,
                                               float* __restrict__ pmom,
                                               float* __restrict__ gdeg,
                                               int* __restrict__ glist,
                                               int* __restrict__ gcnt) {
    __shared__ int   list[LCAP];
    __shared__ int   cnt;
    __shared__ float agg[RPB * 2];
    __shared__ int   degs[RPB];
    __shared__ float pm[5];
    const int t = threadIdx.x, base = blockIdx.x * RPB;
    if (t == 0) cnt = 0;
    if (t < RPB * 2) agg[t] = 0.f;
    if (t < RPB) degs[t] = 0;
    if (t < 5) pm[t] = 0.f;
    __syncthreads();
    // single scan of all edges; record hits on own 9 rows
    for (int e = t; e < NE; e += NTHR) {
        int dst = ei[NE + e];
        unsigned d = (unsigned)(dst - base);
        if (d < RPB) {
            int idx = atomicAdd(&cnt, 1);
            list[idx] = (int)((d << 16) | (unsigned)ei[e]);
            atomicAdd(&degs[d], 1);
        }
    }
    __syncthreads();
    const int n = cnt;
    for (int idx = t; idx < n; idx += NTHR) {
        int pk = list[idx];
        int rr = pk >> 16, src = pk & 0xFFFF;
        float2 xv = ((const float2*)x)[src];
        atomicAdd(&agg[rr * 2],     xv.x);
        atomicAdd(&agg[rr * 2 + 1], xv.y);
    }
    for (int idx = t; idx < n; idx += NTHR) glist[blockIdx.x * LCAP + idx] = list[idx];
    __syncthreads();
    if (t < RPB) {
        int r = base + t;
        float u0 = x[r * 2]     + agg[t * 2];
        float u1 = x[r * 2 + 1] + agg[t * 2 + 1];
        u[r * 2] = u0; u[r * 2 + 1] = u1;
        gdeg[r] = (float)degs[t];
        atomicAdd(&pm[0], u0);      atomicAdd(&pm[1], u1);
        atomicAdd(&pm[2], u0 * u0); atomicAdd(&pm[3], u1 * u1);
        atomicAdd(&pm[4], u0 * u1);
    }
    __syncthreads();
    if (t < 5) pmom[blockIdx.x * 5 + t] = pm[t];
    if (t == 0) gcnt[blockIdx.x] = n;
}

// ==== K1: analytic BN0 + GIN0 mlp + GIN1 aggregate (from hit list) + lin1 + BN1 partials ====
// BN0 stats over tpre0 = u@w1+b1 are exact functions of u's 5 global moments.
// z = y0[own] + sum_e y0[src_e]; layer-1 input = z@g0_w2 + (1+deg)*g0_b2.
// tpre0/h1 never touch global memory; no edge rescan (list precomputed by K0).
__global__ void __launch_bounds__(NTHR) k_gin01(const float* __restrict__ u,
                                                const float* __restrict__ pmom,
                                                const float* __restrict__ gdeg,
                                                const int* __restrict__ glist,
                                                const int* __restrict__ gcnt,
                                                const float* __restrict__ g0_w1,
                                                const float* __restrict__ g0_b1,
                                                const float* __restrict__ g0_gamma,
                                                const float* __restrict__ g0_beta,
                                                const float* __restrict__ g0_w2,
                                                const float* __restrict__ g0_b2,
                                                const float* __restrict__ g1_w1,
                                                const float* __restrict__ g1_b1,
                                                float* __restrict__ tpre1,
                                                float* __restrict__ p1s,
                                                float* __restrict__ p1q) {
    __shared__ float us[NT * 2];      // 14.4 KB
    __shared__ float w2s[4096];       // g0_w2
    __shared__ float w1s[4096];       // g1_w1
    __shared__ float z[RPB * 64];
    __shared__ float t1[RPB * 64];
    __shared__ float mom[20];         // 4 waves x 5 moments
    __shared__ float bn0[128];        // m_c, inv_c
    __shared__ float red[512];

    const int t = threadIdx.x, base = blockIdx.x * RPB;
    const int c = t & 63, rg = t >> 6;

    for (int i = t; i < NT * 2; i += NTHR) us[i] = u[i];
    for (int i = t; i < 4096; i += NTHR) { w2s[i] = g0_w2[i]; w1s[i] = g1_w1[i]; }

    // reduce 200x5 moment partials (register + shuffle, no LDS traffic)
    float s0 = 0, s1 = 0, q00 = 0, q11 = 0, q01 = 0;
    for (int p = t; p < NBLK; p += NTHR) {
        s0 += pmom[p * 5];     s1 += pmom[p * 5 + 1];
        q00 += pmom[p * 5 + 2]; q11 += pmom[p * 5 + 3];
        q01 += pmom[p * 5 + 4];
    }
    for (int off = 32; off > 0; off >>= 1) {
        s0 += __shfl_down(s0, off);   s1 += __shfl_down(s1, off);
        q00 += __shfl_down(q00, off); q11 += __shfl_down(q11, off);
        q01 += __shfl_down(q01, off);
    }
    if (c == 0) {
        mom[rg * 5] = s0; mom[rg * 5 + 1] = s1; mom[rg * 5 + 2] = q00;
        mom[rg * 5 + 3] = q11; mom[rg * 5 + 4] = q01;
    }
    __syncthreads();
    if (t < 64) {
        float S0 = mom[0] + mom[5] + mom[10] + mom[15];
        float S1 = mom[1] + mom[6] + mom[11] + mom[16];
        float Q00 = mom[2] + mom[7] + mom[12] + mom[17];
        float Q11 = mom[3] + mom[8] + mom[13] + mom[18];
        float Q01 = mom[4] + mom[9] + mom[14] + mom[19];
        const float inN = 1.f / NT;
        float mu0 = S0 * inN, mu1 = S1 * inN;
        float c00 = Q00 * inN - mu0 * mu0;
        float c11 = Q11 * inN - mu1 * mu1;
        float c01 = Q01 * inN - mu0 * mu1;
        float w0 = g0_w1[t], w1c = g0_w1[64 + t];
        bn0[t] = g0_b1[t] + mu0 * w0 + mu1 * w1c;                       // channel mean
        float var = w0 * w0 * c00 + 2.f * w0 * w1c * c01 + w1c * w1c * c11;
        bn0[64 + t] = rsqrtf(var + BN_EPS);
    }
    __syncthreads();

    const float w0 = g0_w1[c], w1c = g0_w1[64 + c], b1c = g0_b1[c];
    const float m0 = bn0[c], iv0 = bn0[64 + c];
    const float ga = g0_gamma[c], be = g0_beta[c];
    // z init: own rows' y0
    for (int rr = rg; rr < RPB; rr += 4) {
        int r = base + rr;
        float pre = b1c + us[r * 2] * w0 + us[r * 2 + 1] * w1c;
        z[rr * 64 + c] = fmaxf((pre - m0) * iv0 * ga + be, 0.f);
    }
    __syncthreads();
    // neighbor y0 contributions from precomputed list (wave = edge, lane = channel:
    // z[rr*64+c] across 64 lanes is stride-1 -> 2-way bank aliasing only, free)
    const int n = gcnt[blockIdx.x];
    for (int h = rg; h < n; h += 4) {
        int pk = glist[blockIdx.x * LCAP + h];
        int rr = pk >> 16, src = pk & 0xFFFF;
        float pre = b1c + us[src * 2] * w0 + us[src * 2 + 1] * w1c;
        float y = fmaxf((pre - m0) * iv0 * ga + be, 0.f);
        atomicAdd(&z[rr * 64 + c], y);
    }
    __syncthreads();
    // layer-1 input = z@g0_w2 + (1+deg)*g0_b2
    const float b2c = g0_b2[c];
    for (int rr = rg; rr < RPB; rr += 4) {
        float acc = (1.f + gdeg[base + rr]) * b2c;
#pragma unroll
        for (int k = 0; k < 64; ++k) acc += z[rr * 64 + k] * w2s[k * 64 + c];
        t1[rr * 64 + c] = acc;
    }
    __syncthreads();
    // tpre1 = t1@g1_w1 + b1 ; BN1 stat partials
    const float b1g = g1_b1[c];
    float ls = 0.f, lq = 0.f;
    for (int rr = rg; rr < RPB; rr += 4) {
        float acc = b1g;
#pragma unroll
        for (int k = 0; k < 64; ++k) acc += t1[rr * 64 + k] * w1s[k * 64 + c];
        tpre1[(base + rr) * 64 + c] = acc;
        ls += acc; lq += acc * acc;
    }
    red[t] = ls; red[256 + t] = lq;
    __syncthreads();
    if (t < 64) {
        p1s[blockIdx.x * 64 + t] = red[t] + red[64 + t] + red[128 + t] + red[192 + t];
        p1q[blockIdx.x * 64 + t] = red[256 + t] + red[320 + t] + red[384 + t] + red[448 + t];
    }
}

// ==== K2: BN1 finalize + ReLU + linear 64->64 -> feats + P1/P2 projections + emb partials ====
__global__ void __launch_bounds__(NTHR) k_bnlin1proj(const float* __restrict__ tpre,
                                                     const float* __restrict__ p1s,
                                                     const float* __restrict__ p1q,
                                                     const float* __restrict__ gamma,
                                                     const float* __restrict__ beta,
                                                     const float* __restrict__ w2,
                                                     const float* __restrict__ b2,
                                                     const float* __restrict__ a_w1,
                                                     float* __restrict__ P1,
                                                     float* __restrict__ P2,
                                                     float* __restrict__ pemb,
                                                     float* __restrict__ Sacc,
                                                     int* __restrict__ cntb) {
    __shared__ float y[RPB * 64];
    __shared__ float f[RPB * 64];
    __shared__ float w2s[4096];
    __shared__ float aw1s[4096];
    __shared__ float red[512];
    __shared__ float mi[128];
    const int t = threadIdx.x, base = blockIdx.x * RPB;
    const int c = t & 63, rg = t >> 6;
    // zero the K3 barrier state (visible to K3 via kernel-boundary flush)
    if (blockIdx.x < NB && t == 0) { Sacc[blockIdx.x] = 0.f; cntb[blockIdx.x] = 0; }
    for (int i = t; i < 4096; i += NTHR) { w2s[i] = w2[i]; aw1s[i] = a_w1[64 * HA + i]; }
    float ls = 0.f, lq = 0.f;
    for (int p = rg; p < NBLK; p += 4) { ls += p1s[p * 64 + c]; lq += p1q[p * 64 + c]; }
    red[t] = ls; red[256 + t] = lq;
    __syncthreads();
    if (t < 64) {
        float S = red[t] + red[64 + t] + red[128 + t] + red[192 + t];
        float Q = red[256 + t] + red[320 + t] + red[384 + t] + red[448 + t];
        float m = S * (1.f / NT);
        mi[t] = m;
        mi[64 + t] = rsqrtf(Q * (1.f / NT) - m * m + BN_EPS);
    }
    __syncthreads();
    float m = mi[c], inv = mi[64 + c], ga = gamma[c], be = beta[c];
    for (int rr = rg; rr < RPB; rr += 4) {
        float yv = (tpre[(base + rr) * 64 + c] - m) * inv * ga + be;
        y[rr * 64 + c] = fmaxf(yv, 0.f);
    }
    __syncthreads();
    float bc = b2[c];
    for (int rr = rg; rr < RPB; rr += 4) {
        float acc = bc;
#pragma unroll
        for (int k = 0; k < 64; ++k) acc += y[rr * 64 + k] * w2s[k * 64 + c];
        f[rr * 64 + c] = acc;
    }
    __syncthreads();
    if (t < 64) {    // pooling partial (block's 9 rows are same batch: 225 = 25*9)
        float pe = 0.f;
#pragma unroll
        for (int rr = 0; rr < RPB; ++rr) pe += f[rr * 64 + t];
        pemb[blockIdx.x * 64 + t] = pe;
    }
    int j = c & 31;
    const float* wb = (c < 32) ? aw1s : (aw1s + 64 * HA);
    for (int rr = rg; rr < RPB; rr += 4) {
        float p = 0.f;
#pragma unroll
        for (int k = 0; k < 64; ++k) p += f[rr * 64 + k] * wb[k * HA + j];
        if (c < 32) P1[(base + rr) * HA + j] = p;
        else        P2[(base + rr) * HA + j] = p;
    }
}

// ==== K3: pooled emb + Ps + critic + pairwise exp(logits) + per-batch device barrier + pi ====
__global__ void __launch_bounds__(NTHR) k_pairs(const float* __restrict__ P1,
                                                const float* __restrict__ P2,
                                                const float* __restrict__ pemb,
                                                const float* __restrict__ a_w1,
                                                const float* __restrict__ a_b1,
                                                const float* __restrict__ a_w2,
                                                const float* __restrict__ a_b2,
                                                const float* __restrict__ c_w1,
                                                const float* __restrict__ c_b1,
                                                const float* __restrict__ c_w2,
                                                const float* __restrict__ c_b2,
                                                float* __restrict__ Sacc,
                                                int* __restrict__ cntb,
                                                float* __restrict__ pi,
                                                float* __restrict__ value_out) {
    __shared__ float Q1[NN * 36];    // Ps+P1, stride 36 (16B-aligned)
    __shared__ float P2s[RPB * HA];
    __shared__ float emb[64];
    __shared__ float Psl[32];
    __shared__ float w2l[32];
    __shared__ float hv[32];
    __shared__ float red[256];
    __shared__ float invS;
    const int t = threadIdx.x;
    const int b = blockIdx.x / 25, chunk = blockIdx.x % 25;
    if (t < 64) {
        float s = 0.f;
#pragma unroll
        for (int q = 0; q < 25; ++q) s += pemb[(b * 25 + q) * 64 + t];
        emb[t] = s * (1.f / NN);
    }
    __syncthreads();
    if (t < 32) {
        float a = a_b1[t];
#pragma unroll
        for (int m = 0; m < 64; ++m) a += emb[m] * a_w1[m * HA + t];
        Psl[t] = a;
        w2l[t] = a_w2[t];
    } else if (t < 64 && chunk == 0) {
        int j = t - 32;
        float a = c_b1[j];
#pragma unroll
        for (int m = 0; m < 64; ++m) a += emb[m] * c_w1[m * HC + j];
        hv[j] = fmaxf(a, 0.f);
    }
    __syncthreads();
    if (chunk == 0 && t == 0) {
        float a = c_b2[0];
#pragma unroll
        for (int j = 0; j < HC; ++j) a += hv[j] * c_w2[j];
        value_out[b] = a;
    }
    for (int idx = t; idx < NN * HA; idx += NTHR) {
        int j = idx >> 5, k = idx & 31;
        Q1[j * 36 + k] = Psl[k] + P1[(b * NN + j) * HA + k];
    }
    for (int idx = t; idx < RPB * HA; idx += NTHR)
        P2s[idx] = P2[(b * NN + chunk * RPB) * HA + idx];
    __syncthreads();
    const float bias2 = a_b2[0];
    float ev[8];
    float ls = 0.f;
    for (int p = t, it = 0; p < 2025; p += NTHR, ++it) {
        int i = p / 225, j = p - i * 225;
        const float4* q4 = (const float4*)&Q1[j * 36];
        const float4* p4 = (const float4*)&P2s[i * HA];
        const float4* w4 = (const float4*)w2l;
        float acc = bias2;
#pragma unroll
        for (int k4 = 0; k4 < 8; ++k4) {
            float4 q = q4[k4], pp = p4[k4], w = w4[k4];
            acc += fmaxf(q.x + pp.x, 0.f) * w.x;
            acc += fmaxf(q.y + pp.y, 0.f) * w.y;
            acc += fmaxf(q.z + pp.z, 0.f) * w.z;
            acc += fmaxf(q.w + pp.w, 0.f) * w.w;
        }
        float e = expf(acc);    // logits O(1): no max-subtraction needed in fp32
        ev[it] = e;
        ls += e;
    }
    red[t] = ls;
    __syncthreads();
    for (int s = 128; s > 0; s >>= 1) {
        if (t < s) red[t] += red[t + s];
        __syncthreads();
    }
    // per-batch lightweight device barrier: ev stays in registers across it
    if (t == 0) {
        atomicAdd(&Sacc[b], red[0]);          // device-scope by default
        __threadfence();                       // release partial before arrive
        atomicAdd(&cntb[b], 1);
        int spins = 0;
        while (__hip_atomic_load(&cntb[b], __ATOMIC_RELAXED, __HIP_MEMORY_SCOPE_AGENT) < 25
               && spins < (1 << 18)) ++spins;  // bounded: safety valve
        __threadfence();                       // acquire
        invS = 1.f / __hip_atomic_load(&Sacc[b], __ATOMIC_RELAXED, __HIP_MEMORY_SCOPE_AGENT);
    }
    __syncthreads();
    const float inv = invS;
    float* outp = pi + b * NP + chunk * 2025;
    for (int p = t, it = 0; p < 2025; p += NTHR, ++it)
        outp[p] = ev[it] * inv;
}

extern "C" void kernel_launch(void* const* d_in, const int* in_sizes, int n_in,
                              void* d_out, int out_size, void* d_ws, size_t ws_size,
                              hipStream_t stream) {
    const float* x        = (const float*)d_in[0];
    const int*   ei       = (const int*)d_in[1];
    // d_in[2] = batch_ids (unused: graphs are contiguous 225-node blocks)
    const float* g0_w1    = (const float*)d_in[3];
    const float* g0_b1    = (const float*)d_in[4];
    const float* g0_gamma = (const float*)d_in[5];
    const float* g0_beta  = (const float*)d_in[6];
    const float* g0_w2    = (const float*)d_in[7];
    const float* g0_b2    = (const float*)d_in[8];
    const float* g1_w1    = (const float*)d_in[9];
    const float* g1_b1    = (const float*)d_in[10];
    const float* g1_gamma = (const float*)d_in[11];
    const float* g1_beta  = (const float*)d_in[12];
    const float* g1_w2    = (const float*)d_in[13];
    const float* g1_b2    = (const float*)d_in[14];
    const float* a_w1     = (const float*)d_in[15];
    const float* a_b1     = (const float*)d_in[16];
    const float* a_w2     = (const float*)d_in[17];
    const float* a_b2     = (const float*)d_in[18];
    const float* c_w1     = (const float*)d_in[19];
    const float* c_b1     = (const float*)d_in[20];
    const float* c_w2     = (const float*)d_in[21];
    const float* c_b2     = (const float*)d_in[22];

    float* ws    = (float*)d_ws;
    float* u     = ws + WS_U;
    float* pmom  = ws + WS_PMOM;
    float* gdeg  = ws + WS_DEG;
    int*   glist = (int*)(ws + WS_GL);
    int*   gcnt  = (int*)(ws + WS_GCNT);
    float* tpre1 = ws + WS_TPRE1;
    float* P1    = ws + WS_P1;
    float* P2    = ws + WS_P2;
    float* p1s   = ws + WS_P1S;
    float* p1q   = ws + WS_P1Q;
    float* pemb  = ws + WS_PEMB;
    float* Sacc  = ws + WS_SACC;
    int*   cntb  = (int*)(ws + WS_CNT);

    float* pi        = (float*)d_out;            // [8, 50625]
    float* value_out = (float*)d_out + NB * NP;  // [8]

    k_agg0<<<NBLK, NTHR, 0, stream>>>(x, ei, u, pmom, gdeg, glist, gcnt);
    k_gin01<<<NBLK, NTHR, 0, stream>>>(u, pmom, gdeg, glist, gcnt,
                                       g0_w1, g0_b1, g0_gamma, g0_beta, g0_w2, g0_b2,
                                       g1_w1, g1_b1, tpre1, p1s, p1q);
    k_bnlin1proj<<<NBLK, NTHR, 0, stream>>>(tpre1, p1s, p1q, g1_gamma, g1_beta,
                                            g1_w2, g1_b2, a_w1, P1, P2, pemb, Sacc, cntb);
    k_pairs<<<NBLK, NTHR, 0, stream>>>(P1, P2, pemb, a_w1, a_b1, a_w2, a_b2,
                                       c_w1, c_b1, c_w2, c_b2, Sacc, cntb, pi, value_out);
}